// Round 1
// baseline (55505.823 us; speedup 1.0000x reference)
//
#include <hip/hip_runtime.h>
#include <cstdint>

// Problem constants: D=512, H=2048, T=2048, O=512, 4H=8192.
#define H_DIM 2048
#define H4_DIM 8192
#define T_LEN 2048

__device__ __forceinline__ float sigmoid_f(float x) {
  return 1.0f / (1.0f + __expf(-x));
}
__device__ __forceinline__ float tanh_f(float x) {
  float ax = fabsf(x);
  float e = __expf(-2.0f * ax);
  float r = (1.0f - e) / (1.0f + e);
  return copysignf(r, x);
}

// ---- two-level grid barrier: 256 blocks = 16 groups x 16 blocks ----
// bar[0] = root counter; bar[16 + 16*grp] = group counters (64B apart).
// Monotonic counters (no reset race). Agent scope for cross-XCD coherence.
__device__ __forceinline__ void gridbar(unsigned* bar, unsigned phase, int g) {
  __syncthreads();                       // drains vmcnt: all block stores in L2
  if (threadIdx.x == 0) {
    __threadfence();                     // release: L2 writeback to coherence point
    unsigned* grp = bar + 16 + (g >> 4) * 16;
    unsigned old = __hip_atomic_fetch_add(grp, 1u, __ATOMIC_RELAXED,
                                          __HIP_MEMORY_SCOPE_AGENT);
    if (old == phase * 16u - 1u)         // last of my 16-block group this phase
      __hip_atomic_fetch_add(bar, 1u, __ATOMIC_RELAXED,
                             __HIP_MEMORY_SCOPE_AGENT);
    while (__hip_atomic_load(bar, __ATOMIC_RELAXED,
                             __HIP_MEMORY_SCOPE_AGENT) < phase * 16u)
      __builtin_amdgcn_s_sleep(1);
    __threadfence();                     // acquire: invalidate stale L1/L2
  }
  __syncthreads();
}

// ---- persistent LSTM recurrence, weights register-resident ----
// Grid: 256 blocks x 512 threads. Block g owns hidden indices j = 8g..8g+7.
// Wave w (of 8) owns all 4 gate rows {j, j+2048, j+4096, j+6144} of j = 8g+w.
// Lane l owns columns {4l + 256k + c : k<8, c<4} -> 128 weight VGPRs/thread.
// c_j lives in lane 0's register across all T steps. h double-buffered in
// global (hA = even-step source, zero-initialized here).
__global__ __launch_bounds__(512, 2) void lstm_rec(
    const float* __restrict__ Whh,   // (8192, 2048)
    const float* __restrict__ xp,    // (T, 8192) precomputed x-projection+biases
    float* __restrict__ hA, float* __restrict__ hB,
    float* __restrict__ ys,          // (T, 2048) or nullptr
    unsigned* __restrict__ bar, int T)
{
  __shared__ float hl[H_DIM];
  const int g = blockIdx.x;
  const int tid = threadIdx.x;
  const int w = tid >> 6;
  const int l = tid & 63;
  const int j = g * 8 + w;

  // one-time weight load (each element read exactly once grid-wide)
  float wreg[128];
  #pragma unroll
  for (int q = 0; q < 4; ++q) {
    const float* wr = Whh + (size_t)(j + q * H_DIM) * H_DIM + l * 4;
    #pragma unroll
    for (int k = 0; k < 8; ++k) {
      float4 v = *(const float4*)(wr + 256 * k);
      wreg[q * 32 + k * 4 + 0] = v.x;
      wreg[q * 32 + k * 4 + 1] = v.y;
      wreg[q * 32 + k * 4 + 2] = v.z;
      wreg[q * 32 + k * 4 + 3] = v.w;
    }
  }

  float c = 0.0f;
  if (l == 0) hA[j] = 0.0f;            // h_0 = 0 (each wave zeroes its j)
  gridbar(bar, 1u, g);

  unsigned phase = 2u;
  for (int t = 0; t < T; ++t, ++phase) {
    const float* cur = (t & 1) ? hB : hA;
    float* nxt = (t & 1) ? hA : hB;

    // prefetch this step's x-projection early (consumed after the reduce)
    float xq0 = 0.f, xq1 = 0.f, xq2 = 0.f, xq3 = 0.f;
    if (l == 0) {
      const float* xrow = xp + (size_t)t * H4_DIM + j;
      xq0 = xrow[0];
      xq1 = xrow[H_DIM];
      xq2 = xrow[2 * H_DIM];
      xq3 = xrow[3 * H_DIM];
    }

    // stage h into LDS (8 KB, coalesced float4)
    float4 hv4 = ((const float4*)cur)[tid];
    ((float4*)hl)[tid] = hv4;
    __syncthreads();

    float acc0 = 0.f, acc1 = 0.f, acc2 = 0.f, acc3 = 0.f;
    #pragma unroll
    for (int k = 0; k < 8; ++k) {
      float4 h4 = ((const float4*)hl)[l + 64 * k];
      acc0 = fmaf(wreg[0 + k * 4 + 0], h4.x, acc0);
      acc0 = fmaf(wreg[0 + k * 4 + 1], h4.y, acc0);
      acc0 = fmaf(wreg[0 + k * 4 + 2], h4.z, acc0);
      acc0 = fmaf(wreg[0 + k * 4 + 3], h4.w, acc0);
      acc1 = fmaf(wreg[32 + k * 4 + 0], h4.x, acc1);
      acc1 = fmaf(wreg[32 + k * 4 + 1], h4.y, acc1);
      acc1 = fmaf(wreg[32 + k * 4 + 2], h4.z, acc1);
      acc1 = fmaf(wreg[32 + k * 4 + 3], h4.w, acc1);
      acc2 = fmaf(wreg[64 + k * 4 + 0], h4.x, acc2);
      acc2 = fmaf(wreg[64 + k * 4 + 1], h4.y, acc2);
      acc2 = fmaf(wreg[64 + k * 4 + 2], h4.z, acc2);
      acc2 = fmaf(wreg[64 + k * 4 + 3], h4.w, acc2);
      acc3 = fmaf(wreg[96 + k * 4 + 0], h4.x, acc3);
      acc3 = fmaf(wreg[96 + k * 4 + 1], h4.y, acc3);
      acc3 = fmaf(wreg[96 + k * 4 + 2], h4.z, acc3);
      acc3 = fmaf(wreg[96 + k * 4 + 3], h4.w, acc3);
    }

    // 64-lane butterfly reduce (4 gate dots)
    #pragma unroll
    for (int off = 32; off; off >>= 1) {
      acc0 += __shfl_xor(acc0, off);
      acc1 += __shfl_xor(acc1, off);
      acc2 += __shfl_xor(acc2, off);
      acc3 += __shfl_xor(acc3, off);
    }

    if (l == 0) {
      float i_ = sigmoid_f(acc0 + xq0);
      float f_ = sigmoid_f(acc1 + xq1);
      float g_ = tanh_f(acc2 + xq2);
      float o_ = sigmoid_f(acc3 + xq3);
      c = f_ * c + i_ * g_;
      float h_ = o_ * tanh_f(c);
      nxt[j] = h_;
      if (ys) ys[(size_t)t * H_DIM + j] = h_;
    }
    gridbar(bar, phase, g);  // release h; double-buffer makes 1 barrier enough
  }
}

// ---- fp32 GEMM: C[M][N] = A[M][K] @ W[N][K]^T + b0[n] + b1[n] ----
// 128x128 tile, 256 threads, 8x8 microtile, BK=8.
__global__ __launch_bounds__(256) void gemm_bt_bias(
    const float* __restrict__ A, const float* __restrict__ W,
    const float* __restrict__ b0, const float* __restrict__ b1,
    float* __restrict__ C, int M, int N, int K)
{
  __shared__ float As[8][128];
  __shared__ float Bs[8][128];
  const int tid = threadIdx.x;
  const int n0 = blockIdx.x * 128;
  const int m0 = blockIdx.y * 128;
  const int tx = tid & 15;   // n direction
  const int ty = tid >> 4;   // m direction
  const int lr = tid >> 1;   // loader row 0..127
  const int lk = (tid & 1) * 4;
  const float* Ap = A + (size_t)(m0 + lr) * K + lk;
  const float* Wp = W + (size_t)(n0 + lr) * K + lk;

  float acc[8][8];
  #pragma unroll
  for (int i = 0; i < 8; ++i)
    #pragma unroll
    for (int jj = 0; jj < 8; ++jj) acc[i][jj] = 0.f;

  for (int kt = 0; kt < K; kt += 8) {
    float4 av = *(const float4*)(Ap + kt);
    float4 wv = *(const float4*)(Wp + kt);
    __syncthreads();
    As[lk + 0][lr] = av.x; As[lk + 1][lr] = av.y;
    As[lk + 2][lr] = av.z; As[lk + 3][lr] = av.w;
    Bs[lk + 0][lr] = wv.x; Bs[lk + 1][lr] = wv.y;
    Bs[lk + 2][lr] = wv.z; Bs[lk + 3][lr] = wv.w;
    __syncthreads();
    #pragma unroll
    for (int k = 0; k < 8; ++k) {
      float a[8], b[8];
      *(float4*)&a[0] = *(const float4*)&As[k][ty * 8];
      *(float4*)&a[4] = *(const float4*)&As[k][ty * 8 + 4];
      *(float4*)&b[0] = *(const float4*)&Bs[k][tx * 8];
      *(float4*)&b[4] = *(const float4*)&Bs[k][tx * 8 + 4];
      #pragma unroll
      for (int i = 0; i < 8; ++i)
        #pragma unroll
        for (int jj = 0; jj < 8; ++jj)
          acc[i][jj] = fmaf(a[i], b[jj], acc[i][jj]);
    }
  }

  const int n = n0 + tx * 8;
  float bias[8];
  #pragma unroll
  for (int jj = 0; jj < 8; ++jj)
    bias[jj] = b0[n + jj] + (b1 ? b1[n + jj] : 0.f);
  #pragma unroll
  for (int i = 0; i < 8; ++i) {
    float* crow = C + (size_t)(m0 + ty * 8 + i) * N + n;
    float4 v0 = make_float4(acc[i][0] + bias[0], acc[i][1] + bias[1],
                            acc[i][2] + bias[2], acc[i][3] + bias[3]);
    float4 v1 = make_float4(acc[i][4] + bias[4], acc[i][5] + bias[5],
                            acc[i][6] + bias[6], acc[i][7] + bias[7]);
    *(float4*)crow = v0;
    *(float4*)(crow + 4) = v1;
  }
}

// ---- final FC: out[o] = dot(h, fc_w[o]) + fc_b[o], one wave per output ----
__global__ void fc_kernel(const float* __restrict__ h,
                          const float* __restrict__ Wf,
                          const float* __restrict__ bf,
                          float* __restrict__ out)
{
  const int o = blockIdx.x;
  const int l = threadIdx.x;
  const float* wr = Wf + (size_t)o * H_DIM;
  float s = 0.f;
  #pragma unroll
  for (int k = 0; k < 32; ++k)
    s = fmaf(wr[l + 64 * k], h[l + 64 * k], s);
  #pragma unroll
  for (int off = 32; off; off >>= 1) s += __shfl_xor(s, off);
  if (l == 0) out[o] = s + bf[o];
}

extern "C" void kernel_launch(void* const* d_in, const int* in_sizes, int n_in,
                              void* d_out, int out_size, void* d_ws, size_t ws_size,
                              hipStream_t stream) {
  const float* x    = (const float*)d_in[0];
  const float* Wih0 = (const float*)d_in[1];
  const float* Whh0 = (const float*)d_in[2];
  const float* bih0 = (const float*)d_in[3];
  const float* bhh0 = (const float*)d_in[4];
  const float* Wih1 = (const float*)d_in[5];
  const float* Whh1 = (const float*)d_in[6];
  const float* bih1 = (const float*)d_in[7];
  const float* bhh1 = (const float*)d_in[8];
  const float* fcw  = (const float*)d_in[9];
  const float* fcb  = (const float*)d_in[10];
  float* out = (float*)d_out;

  // workspace layout (floats): needs ~84 MB
  float* ws  = (float*)d_ws;
  float* xp  = ws;                       // 2048*8192 = 16777216
  float* ys  = ws + 16777216;            // 2048*2048 =  4194304
  float* hA0 = ws + 20971520;
  float* hB0 = hA0 + H_DIM;
  float* hA1 = hB0 + H_DIM;
  float* hB1 = hA1 + H_DIM;
  unsigned* bar = (unsigned*)(ws + 20979712);  // 2 regions x 512 uints

  hipMemsetAsync(bar, 0, 4096, stream);  // zero barrier counters (ws is poisoned)

  dim3 gblk(256);
  dim3 ggrid(H4_DIM / 128, T_LEN / 128);  // (64, 16)

  // layer 0: xp = x @ Wih0^T + (bih0+bhh0); then recurrence -> ys
  gemm_bt_bias<<<ggrid, gblk, 0, stream>>>(x, Wih0, bih0, bhh0, xp,
                                           T_LEN, H4_DIM, 512);
  lstm_rec<<<256, 512, 0, stream>>>(Whh0, xp, hA0, hB0, ys, bar, T_LEN);

  // layer 1: xp = ys @ Wih1^T + (bih1+bhh1); recurrence, keep only h_last
  gemm_bt_bias<<<ggrid, gblk, 0, stream>>>(ys, Wih1, bih1, bhh1, xp,
                                           T_LEN, H4_DIM, H_DIM);
  lstm_rec<<<256, 512, 0, stream>>>(Whh1, xp, hA1, hB1, nullptr, bar + 512, T_LEN);

  // h_last of layer 1 ends in hA1 (T even: last write -> buffer A)
  fc_kernel<<<512, 64, 0, stream>>>(hA1, fcw, fcb, out);
}

// Round 2
// 13778.583 us; speedup vs baseline: 4.0284x; 4.0284x over previous
//
#include <hip/hip_runtime.h>
#include <cstdint>

// Problem constants: D=512, H=2048, T=2048, O=512, 4H=8192.
#define H_DIM 2048
#define H4_DIM 8192
#define T_LEN 2048

typedef unsigned long long u64;

__device__ __forceinline__ float sigmoid_f(float x) {
  return 1.0f / (1.0f + __expf(-x));
}
__device__ __forceinline__ float tanh_f(float x) {
  float ax = fabsf(x);
  float e = __expf(-2.0f * ax);
  float r = (1.0f - e) / (1.0f + e);
  return copysignf(r, x);
}

// ---- persistent LSTM recurrence, weights register-resident, NO barrier ----
// Cross-step exchange: slot[parity][j] holds (tag<<32)|bits(h_j), written with
// relaxed agent-scope 64-bit atomic stores (write-through to LLC), read with
// relaxed agent-scope 64-bit atomic loads. Tag==t gates consumption; parity
// double-buffer + the all-to-all dependence makes overwrite-before-read
// impossible (a block can publish h_{t+2} only after every block consumed h_t).
// 0xAAAAAAAA poison never matches tags 1..2048, so no init needed.
//
// Grid: 256 blocks x 512 threads. Block g owns hidden j = 8g..8g+7; wave w
// owns all 4 gate rows of j = 8g+w; lane l owns cols {4l+256k+c}. c_j stays
// in lane 0's register for all T steps.
__global__ __launch_bounds__(512, 2) void lstm_rec(
    const float* __restrict__ Whh,   // (8192, 2048)
    const float* __restrict__ xp,    // (T, 8192) x-projection + biases
    u64* __restrict__ slots,         // 2 * 2048 tagged h slots
    float* __restrict__ ys,          // (T, 2048) or nullptr
    int T)
{
  __shared__ float hl[H_DIM];
  const int g = blockIdx.x;
  const int tid = threadIdx.x;
  const int w = tid >> 6;
  const int l = tid & 63;
  const int j = g * 8 + w;

  // one-time weight load (each element read exactly once grid-wide)
  float wreg[128];
  #pragma unroll
  for (int q = 0; q < 4; ++q) {
    const float* wr = Whh + (size_t)(j + q * H_DIM) * H_DIM + l * 4;
    #pragma unroll
    for (int k = 0; k < 8; ++k) {
      float4 v = *(const float4*)(wr + 256 * k);
      wreg[q * 32 + k * 4 + 0] = v.x;
      wreg[q * 32 + k * 4 + 1] = v.y;
      wreg[q * 32 + k * 4 + 2] = v.z;
      wreg[q * 32 + k * 4 + 3] = v.w;
    }
  }

  float c = 0.0f;

  for (int t = 0; t < T; ++t) {
    // prefetch this step's x-projection early (consumed after the reduce)
    float xq0 = 0.f, xq1 = 0.f, xq2 = 0.f, xq3 = 0.f;
    if (l == 0) {
      const float* xrow = xp + (size_t)t * H4_DIM + j;
      xq0 = xrow[0];
      xq1 = xrow[H_DIM];
      xq2 = xrow[2 * H_DIM];
      xq3 = xrow[3 * H_DIM];
    }

    if (t == 0) {
      // h_0 = 0, known everywhere: no exchange
      hl[tid] = 0.f; hl[tid + 512] = 0.f;
      hl[tid + 1024] = 0.f; hl[tid + 1536] = 0.f;
    } else {
      // consume h_t: poll 4 slots (coalesced: lane-consecutive u64)
      const u64* S = slots + (size_t)(t & 1) * H_DIM;
      unsigned pend = 0xFu;
      while (pend) {
        #pragma unroll
        for (int s = 0; s < 4; ++s) {
          if (pend & (1u << s)) {
            u64 v = __hip_atomic_load(S + tid + 512 * s, __ATOMIC_RELAXED,
                                      __HIP_MEMORY_SCOPE_AGENT);
            if ((unsigned)(v >> 32) == (unsigned)t) {
              union { unsigned u; float f; } cv;
              cv.u = (unsigned)v;
              hl[tid + 512 * s] = cv.f;
              pend &= ~(1u << s);
            }
          }
        }
        if (pend) __builtin_amdgcn_s_sleep(1);
      }
    }
    __syncthreads();

    float acc0 = 0.f, acc1 = 0.f, acc2 = 0.f, acc3 = 0.f;
    #pragma unroll
    for (int k = 0; k < 8; ++k) {
      float4 h4 = ((const float4*)hl)[l + 64 * k];
      acc0 = fmaf(wreg[0 + k * 4 + 0], h4.x, acc0);
      acc0 = fmaf(wreg[0 + k * 4 + 1], h4.y, acc0);
      acc0 = fmaf(wreg[0 + k * 4 + 2], h4.z, acc0);
      acc0 = fmaf(wreg[0 + k * 4 + 3], h4.w, acc0);
      acc1 = fmaf(wreg[32 + k * 4 + 0], h4.x, acc1);
      acc1 = fmaf(wreg[32 + k * 4 + 1], h4.y, acc1);
      acc1 = fmaf(wreg[32 + k * 4 + 2], h4.z, acc1);
      acc1 = fmaf(wreg[32 + k * 4 + 3], h4.w, acc1);
      acc2 = fmaf(wreg[64 + k * 4 + 0], h4.x, acc2);
      acc2 = fmaf(wreg[64 + k * 4 + 1], h4.y, acc2);
      acc2 = fmaf(wreg[64 + k * 4 + 2], h4.z, acc2);
      acc2 = fmaf(wreg[64 + k * 4 + 3], h4.w, acc2);
      acc3 = fmaf(wreg[96 + k * 4 + 0], h4.x, acc3);
      acc3 = fmaf(wreg[96 + k * 4 + 1], h4.y, acc3);
      acc3 = fmaf(wreg[96 + k * 4 + 2], h4.z, acc3);
      acc3 = fmaf(wreg[96 + k * 4 + 3], h4.w, acc3);
    }

    // 64-lane butterfly reduce (4 gate dots)
    #pragma unroll
    for (int off = 32; off; off >>= 1) {
      acc0 += __shfl_xor(acc0, off);
      acc1 += __shfl_xor(acc1, off);
      acc2 += __shfl_xor(acc2, off);
      acc3 += __shfl_xor(acc3, off);
    }

    if (l == 0) {
      float i_ = sigmoid_f(acc0 + xq0);
      float f_ = sigmoid_f(acc1 + xq1);
      float g_ = tanh_f(acc2 + xq2);
      float o_ = sigmoid_f(acc3 + xq3);
      c = f_ * c + i_ * g_;
      float h_ = o_ * tanh_f(c);
      // publish h_{t+1} ASAP (tagged, single 8B atomic -> LLC)
      union { float f; unsigned u; } cv;
      cv.f = h_;
      u64 pv = ((u64)(unsigned)(t + 1) << 32) | (u64)cv.u;
      __hip_atomic_store(slots + (size_t)((t + 1) & 1) * H_DIM + j, pv,
                         __ATOMIC_RELAXED, __HIP_MEMORY_SCOPE_AGENT);
      if (ys) ys[(size_t)t * H_DIM + j] = h_;
    }
    // all waves must finish reading hl before next step's poll overwrites it
    __syncthreads();
  }
}

// ---- fp32 GEMM: C[M][N] = A[M][K] @ W[N][K]^T + b0[n] + b1[n] ----
// 128x128 tile, 256 threads, 8x8 microtile, BK=8.
__global__ __launch_bounds__(256) void gemm_bt_bias(
    const float* __restrict__ A, const float* __restrict__ W,
    const float* __restrict__ b0, const float* __restrict__ b1,
    float* __restrict__ C, int M, int N, int K)
{
  __shared__ float As[8][128];
  __shared__ float Bs[8][128];
  const int tid = threadIdx.x;
  const int n0 = blockIdx.x * 128;
  const int m0 = blockIdx.y * 128;
  const int tx = tid & 15;   // n direction
  const int ty = tid >> 4;   // m direction
  const int lr = tid >> 1;   // loader row 0..127
  const int lk = (tid & 1) * 4;
  const float* Ap = A + (size_t)(m0 + lr) * K + lk;
  const float* Wp = W + (size_t)(n0 + lr) * K + lk;

  float acc[8][8];
  #pragma unroll
  for (int i = 0; i < 8; ++i)
    #pragma unroll
    for (int jj = 0; jj < 8; ++jj) acc[i][jj] = 0.f;

  for (int kt = 0; kt < K; kt += 8) {
    float4 av = *(const float4*)(Ap + kt);
    float4 wv = *(const float4*)(Wp + kt);
    __syncthreads();
    As[lk + 0][lr] = av.x; As[lk + 1][lr] = av.y;
    As[lk + 2][lr] = av.z; As[lk + 3][lr] = av.w;
    Bs[lk + 0][lr] = wv.x; Bs[lk + 1][lr] = wv.y;
    Bs[lk + 2][lr] = wv.z; Bs[lk + 3][lr] = wv.w;
    __syncthreads();
    #pragma unroll
    for (int k = 0; k < 8; ++k) {
      float a[8], b[8];
      *(float4*)&a[0] = *(const float4*)&As[k][ty * 8];
      *(float4*)&a[4] = *(const float4*)&As[k][ty * 8 + 4];
      *(float4*)&b[0] = *(const float4*)&Bs[k][tx * 8];
      *(float4*)&b[4] = *(const float4*)&Bs[k][tx * 8 + 4];
      #pragma unroll
      for (int i = 0; i < 8; ++i)
        #pragma unroll
        for (int jj = 0; jj < 8; ++jj)
          acc[i][jj] = fmaf(a[i], b[jj], acc[i][jj]);
    }
  }

  const int n = n0 + tx * 8;
  float bias[8];
  #pragma unroll
  for (int jj = 0; jj < 8; ++jj)
    bias[jj] = b0[n + jj] + (b1 ? b1[n + jj] : 0.f);
  #pragma unroll
  for (int i = 0; i < 8; ++i) {
    float* crow = C + (size_t)(m0 + ty * 8 + i) * N + n;
    float4 v0 = make_float4(acc[i][0] + bias[0], acc[i][1] + bias[1],
                            acc[i][2] + bias[2], acc[i][3] + bias[3]);
    float4 v1 = make_float4(acc[i][4] + bias[4], acc[i][5] + bias[5],
                            acc[i][6] + bias[6], acc[i][7] + bias[7]);
    *(float4*)crow = v0;
    *(float4*)(crow + 4) = v1;
  }
}

// ---- final FC: out[o] = dot(h_last, fc_w[o]) + fc_b[o], one wave/output ----
// h_last read from layer-1 tagged slots (parity 0, tag T), low 32 bits.
__global__ void fc_kernel(const u64* __restrict__ hslots,
                          const float* __restrict__ Wf,
                          const float* __restrict__ bf,
                          float* __restrict__ out)
{
  const int o = blockIdx.x;
  const int l = threadIdx.x;
  const float* wr = Wf + (size_t)o * H_DIM;
  float s = 0.f;
  #pragma unroll
  for (int k = 0; k < 32; ++k) {
    union { unsigned u; float f; } cv;
    cv.u = (unsigned)hslots[l + 64 * k];
    s = fmaf(wr[l + 64 * k], cv.f, s);
  }
  #pragma unroll
  for (int off = 32; off; off >>= 1) s += __shfl_xor(s, off);
  if (l == 0) out[o] = s + bf[o];
}

extern "C" void kernel_launch(void* const* d_in, const int* in_sizes, int n_in,
                              void* d_out, int out_size, void* d_ws, size_t ws_size,
                              hipStream_t stream) {
  const float* x    = (const float*)d_in[0];
  const float* Wih0 = (const float*)d_in[1];
  const float* Whh0 = (const float*)d_in[2];
  const float* bih0 = (const float*)d_in[3];
  const float* bhh0 = (const float*)d_in[4];
  const float* Wih1 = (const float*)d_in[5];
  const float* Whh1 = (const float*)d_in[6];
  const float* bih1 = (const float*)d_in[7];
  const float* bhh1 = (const float*)d_in[8];
  const float* fcw  = (const float*)d_in[9];
  const float* fcb  = (const float*)d_in[10];
  float* out = (float*)d_out;

  // workspace layout (floats): ~84 MB
  float* ws  = (float*)d_ws;
  float* xp  = ws;                       // 2048*8192 = 16777216
  float* ys  = ws + 16777216;            // 2048*2048 =  4194304
  u64* slots0 = (u64*)(ws + 20971520);   // 2 parities x 2048 tagged h (32 KB)
  u64* slots1 = slots0 + 2 * H_DIM;      // layer 1 (separate: fresh poison)

  dim3 gblk(256);
  dim3 ggrid(H4_DIM / 128, T_LEN / 128);  // (64, 16)

  // layer 0: xp = x @ Wih0^T + (bih0+bhh0); recurrence -> ys
  gemm_bt_bias<<<ggrid, gblk, 0, stream>>>(x, Wih0, bih0, bhh0, xp,
                                           T_LEN, H4_DIM, 512);
  lstm_rec<<<256, 512, 0, stream>>>(Whh0, xp, slots0, ys, T_LEN);

  // layer 1: xp = ys @ Wih1^T + (bih1+bhh1); recurrence, keep only h_last
  gemm_bt_bias<<<ggrid, gblk, 0, stream>>>(ys, Wih1, bih1, bhh1, xp,
                                           T_LEN, H4_DIM, H_DIM);
  lstm_rec<<<256, 512, 0, stream>>>(Whh1, xp, slots1, nullptr, T_LEN);

  // h_last of layer 1: slots1 parity (T&1)=0, tag T
  fc_kernel<<<512, 64, 0, stream>>>(slots1, fcw, fcb, out);
}